// Round 9
// baseline (227.631 us; speedup 1.0000x reference)
//
#include <hip/hip_runtime.h>

// PerturbedTopK: x(32,2048) f32, noise(32,500,2048) f32.
// out = [indicators (32,128,2048) f32, idx (32,500,128) as f32], concatenated.
//
// R9: 4 waves per row in select (512 elems / 8 per lane each) -> 64000 waves
// of memory-level parallelism (R8's 2-wave split gave -8us; occupancy is the
// protective variable per R6/R8 evidence). Each quarter compacts candidates
// (>= per-b 160th-quantile cutoff) into its own clamped LDS region; wave 0
// stitches all four (ascending index preserved) and runs the ballot radix
// select + emission. Fallback (C outside [128,256], ~7sigma): wave 0 reloads
// the full row, verified R1 path. Hist: JCHUNK=4 (32KB LDS, 1024 blocks) for
// higher per-CU concurrency at identical traffic.

constexpr int B_     = 32;
constexpr int D_     = 2048;
constexpr int NS_    = 500;
constexpr int TOPK_  = 128;
constexpr int SLACK_ = 32;               // cutoff rank = 160
constexpr float SIGMA_  = 0.05f;
constexpr int PER_LANE_ = D_ / 64;       // 32 (fallback/cutoff)
constexpr int QTR_   = D_ / 4;           // 512
constexpr int QPL_   = QTR_ / 64;        // 8 elements per lane per quarter
constexpr int CAP_   = 256;              // fast-path candidate cap (4 slots)
constexpr int SLOTS_ = CAP_ / 64;        // 4
constexpr int JCHUNK_ = 4;               // ranks per hist block

__device__ __forceinline__ uint32_t order_key(float f) {
  uint32_t u = __float_as_uint(f);
  return (u & 0x80000000u) ? ~u : (u | 0x80000000u);
}
__device__ __forceinline__ float inv_key(uint32_t k) {
  uint32_t u = (k & 0x80000000u) ? (k & 0x7FFFFFFFu) : ~k;
  return __uint_as_float(u);
}

// ---- kernel 1: per-b cutoff = exact (TOPK_+SLACK_)th largest of x_b ----
__global__ __launch_bounds__(64) void ptk_cutoff(const float* __restrict__ x,
                                                 float* __restrict__ cutf) {
  const int lane = threadIdx.x & 63;
  const int b = blockIdx.x;
  const float* __restrict__ xr = x + (size_t)b * D_;
  uint32_t keys[PER_LANE_];
#pragma unroll
  for (int j = 0; j < PER_LANE_; j += 4) {
    const float4 xv = *reinterpret_cast<const float4*>(xr + lane * PER_LANE_ + j);
    keys[j + 0] = order_key(xv.x); keys[j + 1] = order_key(xv.y);
    keys[j + 2] = order_key(xv.z); keys[j + 3] = order_key(xv.w);
  }
  uint32_t prefix = 0; int k = TOPK_ + SLACK_;
#pragma unroll 1
  for (int bit = 31; bit >= 0; --bit) {
    const uint32_t want = (prefix >> bit) | 1u;
    int c = 0;
#pragma unroll
    for (int j = 0; j < PER_LANE_; ++j) c += ((keys[j] >> bit) == want) ? 1 : 0;
#pragma unroll
    for (int off = 32; off >= 1; off >>= 1) c += __shfl_xor(c, off);
    if (c >= k) prefix |= (1u << bit); else k -= c;
  }
  if (lane == 0) cutf[b] = inv_key(prefix);
}

// ---- kernel 2: selection, 4 waves per row (one row per block) ----
__global__ __launch_bounds__(256) void ptk_select(
    const float* __restrict__ x, const float* __restrict__ noise,
    const float* __restrict__ cutf, float* __restrict__ out_idx) {
  __shared__ uint2 comp[4 * CAP_];   // 8 KB: one clamped region per quarter
  __shared__ int cnts[4];

  const int lane = threadIdx.x & 63;
  const int wave = threadIdx.x >> 6;       // quarter 0..3
  const int row  = blockIdx.x;             // 0..15999
  const int b = row / NS_;

  const float* __restrict__ xr = x + (size_t)b * D_ + wave * QTR_;
  const float* __restrict__ nr = noise + (size_t)row * D_ + wave * QTR_;
  const int base_l = lane * QPL_;          // within quarter
  const int base_i = wave * QTR_ + base_l;

  float p[QPL_];
#pragma unroll
  for (int j = 0; j < QPL_; j += 4) {
    const float4 nv = *reinterpret_cast<const float4*>(nr + base_l + j);
    const float4 xv = *reinterpret_cast<const float4*>(xr + base_l + j);
    p[j + 0] = fmaf(SIGMA_, nv.x, xv.x);
    p[j + 1] = fmaf(SIGMA_, nv.y, xv.y);
    p[j + 2] = fmaf(SIGMA_, nv.z, xv.z);
    p[j + 3] = fmaf(SIGMA_, nv.w, xv.w);
  }

  const float cf = cutf[b];   // wave-uniform

  uint32_t m = 0;
#pragma unroll
  for (int j = 0; j < QPL_; ++j) m |= (p[j] >= cf) ? (1u << j) : 0u;
  const int cnt = __popc(m);

  // ballot-based exclusive scan of cnt (4 bits, cnt<=8) -> offset, total Cw
  const uint64_t below = (lane == 0) ? 0ull : ((~0ull) >> (64 - lane));
  int offset = 0, Cw = 0;
#pragma unroll
  for (int t = 0; t < 4; ++t) {
    const uint64_t mb = __ballot((cnt >> t) & 1);
    offset += (int)__popcll(mb & below) << t;
    Cw     += (int)__popcll(mb) << t;
  }
  if (lane == 0) cnts[wave] = Cw;

  // compact this quarter's candidates (ascending index) into its region;
  // clamp to CAP_ (overflow => C > CAP_ => fallback ignores comp anyway)
  {
    uint32_t mm = m; int q = offset;
    while (mm) {
      const int j = __ffs(mm) - 1; mm &= mm - 1;
      if (q < CAP_)
        comp[wave * CAP_ + q] = make_uint2(order_key(p[j]),
                                           (uint32_t)(base_i + j));
      ++q;
    }
  }
  __syncthreads();

  if (wave) return;   // waves 1..3 retire; wave 0 finishes the row

  const int C0 = cnts[0], C1 = cnts[1], C2 = cnts[2], C3 = cnts[3];
  const int s1 = C0, s2 = C0 + C1, s3 = C0 + C1 + C2;
  const int C  = s3 + C3;

  float* __restrict__ idx_row = out_idx + (size_t)row * TOPK_;

  if (C >= TOPK_ && C <= CAP_) {
    // ---------- fast path: stitch 4 regions (ordinal = index quarter) ----------
    uint32_t kk[SLOTS_], ki[SLOTS_];
    bool valid[SLOTS_];
#pragma unroll
    for (int s = 0; s < SLOTS_; ++s) {
      const int q = (s << 6) + lane;
      int a;
      if (q < s1)      a = q;
      else if (q < s2) a = CAP_     + (q - s1);
      else if (q < s3) a = 2 * CAP_ + (q - s2);
      else             a = 3 * CAP_ + (q - s3);
      valid[s] = (q < C);
      const uint2 v = valid[s] ? comp[a] : make_uint2(0u, 0u);
      kk[s] = v.x; ki[s] = v.y;   // pad key 0 never matches a radix class
    }

    // common-prefix skip: and/or reduce over candidate keys
    uint32_t orv = 0u, andv = 0xFFFFFFFFu;
#pragma unroll
    for (int s = 0; s < SLOTS_; ++s) {
      orv  |= valid[s] ? kk[s] : 0u;
      andv &= valid[s] ? kk[s] : 0xFFFFFFFFu;
    }
#pragma unroll
    for (int off = 32; off >= 1; off >>= 1) {
      orv  |= __shfl_xor(orv, off);
      andv &= __shfl_xor(andv, off);
    }
    const uint32_t diff = orv ^ andv;

    uint32_t prefix; int r;
    if (diff == 0u) {
      prefix = orv; r = TOPK_;
    } else {
      const int startbit = 31 - __clz(diff);
      prefix = (startbit == 31) ? 0u : (andv & (0xFFFFFFFFu << (startbit + 1)));
      int k = TOPK_;
      int A = C;
#pragma unroll 1
      for (int bit = startbit; bit >= 0; --bit) {
        const uint32_t want = (prefix >> bit) | 1u;
        int c = 0;
#pragma unroll
        for (int s = 0; s < SLOTS_; ++s)
          c += __popcll(__ballot((kk[s] >> bit) == want));
        if (c >= k) { prefix |= (1u << bit); A = c; }
        else        { k -= c; A -= c; }
        if (A == 1) {
          uint32_t mykey = 0u; bool have = false;
#pragma unroll
          for (int s = 0; s < SLOTS_; ++s) {
            const bool hit = valid[s] && ((kk[s] >> bit) == (prefix >> bit));
            mykey = hit ? kk[s] : mykey;
            have |= hit;
          }
          const uint64_t mb = __ballot(have);
          const int src = __ffsll((unsigned long long)mb) - 1;
          prefix = __shfl(mykey, src);
          k = 1;
          break;
        }
      }
      r = k;
    }

    // ballot-ranked emission, ascending index order
    int sel_run = 0, eq_run = 0;
#pragma unroll
    for (int s = 0; s < SLOTS_; ++s) {
      const bool gt = kk[s] > prefix;
      const bool eq = kk[s] == prefix;
      const uint64_t meq = __ballot(eq);
      const int eqrank = eq_run + __popcll(meq & below);
      const bool sel = gt || (eq && (eqrank < r));
      const uint64_t msel = __ballot(sel);
      if (sel) {
        const int pos = sel_run + __popcll(msel & below);
        idx_row[pos] = (float)(int)ki[s];
      }
      sel_run += __popcll(msel);
      eq_run  += __popcll(meq);
    }
  } else {
    // ---------- fallback (rare): wave 0 reloads full row, R1 exact ----------
    const float* __restrict__ xr2 = x + (size_t)b * D_;
    const float* __restrict__ nr2 = noise + (size_t)row * D_;
    const int bi = lane * PER_LANE_;
    uint32_t keys[PER_LANE_];
#pragma unroll
    for (int j = 0; j < PER_LANE_; ++j)
      keys[j] = order_key(fmaf(SIGMA_, nr2[bi + j], xr2[bi + j]));

    uint32_t prefix = 0; int k = TOPK_;
#pragma unroll 1
    for (int bit = 31; bit >= 0; --bit) {
      const uint32_t want = (prefix >> bit) | 1u;
      int c = 0;
#pragma unroll
      for (int j = 0; j < PER_LANE_; ++j) c += ((keys[j] >> bit) == want) ? 1 : 0;
#pragma unroll
      for (int off = 32; off >= 1; off >>= 1) c += __shfl_xor(c, off);
      if (c >= k) prefix |= (1u << bit); else k -= c;
    }
    const int r = k;

    int gt = 0, eq = 0;
#pragma unroll
    for (int j = 0; j < PER_LANE_; ++j) {
      gt += (keys[j] > prefix) ? 1 : 0;
      eq += (keys[j] == prefix) ? 1 : 0;
    }
    uint32_t incl2 = (uint32_t)gt | ((uint32_t)eq << 16);
#pragma unroll
    for (int off = 1; off < 64; off <<= 1) {
      uint32_t y = __shfl_up(incl2, (unsigned)off);
      if (lane >= off) incl2 += y;
    }
    const int gt_base = (int)(incl2 & 0xFFFFu) - gt;
    const int eq_base = (int)(incl2 >> 16) - eq;
    int pos = gt_base + min(eq_base, r);
    int eq_seen = eq_base;
#pragma unroll
    for (int j = 0; j < PER_LANE_; ++j) {
      const uint32_t kj = keys[j];
      bool s = false;
      if (kj > prefix) s = true;
      else if (kj == prefix) { s = (eq_seen < r); eq_seen++; }
      if (s) { idx_row[pos] = (float)(bi + j); pos++; }
    }
  }
}

// ---- kernel 3: histograms -> indicators (writes every element; no memset) ----
__global__ __launch_bounds__(256) void ptk_hist(
    const float* __restrict__ out_idx, float* __restrict__ indicators) {
  __shared__ int hist[JCHUNK_][D_];   // 32 KB

  const int tid   = threadIdx.x;
  const int b     = blockIdx.x >> 5;         // 32 chunks per b
  const int chunk = blockIdx.x & 31;
  const int j0    = chunk * JCHUNK_;

  int4* h4 = (int4*)hist;
  for (int t = tid; t < JCHUNK_ * D_ / 4; t += 256)
    h4[t] = make_int4(0, 0, 0, 0);
  __syncthreads();

  const float* __restrict__ src = out_idx + (size_t)b * NS_ * TOPK_ + j0;
  for (int n = tid; n < NS_; n += 256) {     // one float4 = this block's 4 ranks
    const float4 v = *reinterpret_cast<const float4*>(src + (size_t)n * TOPK_);
    atomicAdd(&hist[0][(int)v.x], 1);
    atomicAdd(&hist[1][(int)v.y], 1);
    atomicAdd(&hist[2][(int)v.z], 1);
    atomicAdd(&hist[3][(int)v.w], 1);
  }
  __syncthreads();

  float4* __restrict__ dst =
      (float4*)(indicators + ((size_t)b * TOPK_ + j0) * D_);
  for (int t = tid; t < JCHUNK_ * D_ / 4; t += 256) {
    const int4 h = h4[t];
    float4 o;
    o.x = (float)h.x / (float)NS_;
    o.y = (float)h.y / (float)NS_;
    o.z = (float)h.z / (float)NS_;
    o.w = (float)h.w / (float)NS_;
    dst[t] = o;
  }
}

extern "C" void kernel_launch(void* const* d_in, const int* in_sizes, int n_in,
                              void* d_out, int out_size, void* d_ws, size_t ws_size,
                              hipStream_t stream) {
  const float* x     = (const float*)d_in[0];
  const float* noise = (const float*)d_in[1];
  float* indicators  = (float*)d_out;
  float* out_idx     = (float*)d_out + (size_t)B_ * TOPK_ * D_;
  float* cutf        = (float*)d_ws;

  hipLaunchKernelGGL(ptk_cutoff, dim3(B_), dim3(64), 0, stream, x, cutf);

  const int rows = B_ * NS_;                        // 16000
  hipLaunchKernelGGL(ptk_select, dim3(rows), dim3(256), 0, stream,
                     x, noise, cutf, out_idx);

  hipLaunchKernelGGL(ptk_hist, dim3(B_ * (TOPK_ / JCHUNK_)), dim3(256), 0,
                     stream, out_idx, indicators);
}